// Round 8
// baseline (541.823 us; speedup 1.0000x reference)
//
#include <hip/hip_runtime.h>
#include <math.h>

#define NBATCH 16
#define SEQL   512
#define DIM    41
#define LDFLAT (SEQL*DIM)   // 20992
#define OBS    4096
#define DK     128
#define NH     4
#define DH     32

typedef short bf16x8 __attribute__((ext_vector_type(8)));
typedef short short8v __attribute__((ext_vector_type(8)));
typedef float floatx4 __attribute__((ext_vector_type(4)));

__device__ __forceinline__ short f2bf(float f) {
  union { float f; unsigned u; } v;
  v.f = f;
  unsigned r = (v.u + 0x7fffu + ((v.u >> 16) & 1u)) >> 16;
  return (short)r;
}
__device__ __forceinline__ float bf2f(short s) {
  union { unsigned u; float f; } v;
  v.u = ((unsigned)(unsigned short)s) << 16;
  return v.f;
}

// ---- shared GEMM building blocks ----
// NOTE (R5/R6 post-mortem): do NOT register-prefetch the next weight matrix.
// vmcnt is ordered; a commit-wait after epilogue stores transitively waits on
// all prior store acks and parks the block (fusedA 45us -> 140us). stage_w
// (plain global->LDS right before use) is the proven-fast pattern.
__device__ __forceinline__ void stage_w(short* Wl, const short* __restrict__ Wt,
                                        int tid) {
#pragma unroll
  for (int i = tid * 8; i < 128 * 128; i += 2048)
    *(int4*)&Wl[(i >> 7) * 136 + (i & 127)] = *(const int4*)&Wt[i];
}
// ---- 64-row (1 m-tile/wave) variants, used by qh path and fusedB ----
__device__ __forceinline__ void load_af(const short* Xl, int wv, int lm,
                                        int quad, bf16x8 af[4]) {
#pragma unroll
  for (int kc = 0; kc < 4; kc++)
    af[kc] = *(bf16x8*)&Xl[(wv * 16 + lm) * 136 + kc * 32 + quad * 8];
}
__device__ __forceinline__ void gemm8(const short* Wl, const bf16x8 af[4],
                                      int lm, int quad, floatx4 acc[8]) {
#pragma unroll
  for (int nt = 0; nt < 8; nt++) acc[nt] = (floatx4){0.f, 0.f, 0.f, 0.f};
#pragma unroll
  for (int kc = 0; kc < 4; kc++) {
    bf16x8 a = af[kc];
#pragma unroll
    for (int nt = 0; nt < 8; nt++) {
      bf16x8 b = *(bf16x8*)&Wl[(nt * 16 + lm) * 136 + kc * 32 + quad * 8];
      acc[nt] = __builtin_amdgcn_mfma_f32_16x16x32_bf16(a, b, acc[nt], 0, 0, 0);
    }
  }
}
__device__ __forceinline__ void store_sl(short* Sl, const floatx4 acc[8],
                                         const float* __restrict__ bias,
                                         int wv, int lm, int quad) {
#pragma unroll
  for (int nt = 0; nt < 8; nt++) {
    int col = nt * 16 + lm;
    float bn = bias[col];
#pragma unroll
    for (int r = 0; r < 4; r++)
      Sl[(wv * 16 + quad * 4 + r) * 136 + col] = f2bf(acc[nt][r] + bn);
  }
}
__device__ __forceinline__ void write_hs(const short* Sl,
                                         short* __restrict__ out, int rb,
                                         int nshift, int tid) {
  int rr = tid >> 2, hh = tid & 3;
  int r = rb + rr;
  int bb = r >> nshift, nn = r & ((1 << nshift) - 1);
  size_t o = (((size_t)(bb * NH + hh) << nshift) + nn) * 32;
#pragma unroll
  for (int j = 0; j < 4; j++)
    *(int4*)&out[o + j * 8] = *(int4*)&Sl[rr * 136 + hh * 32 + j * 8];
}
// ---- 128-row (2 m-tiles/wave) variants ----
__device__ __forceinline__ void gemm16(const short* Wl, const short* Xl,
                                       int wv, int lm, int quad,
                                       floatx4 acc[2][8]) {
  bf16x8 af[2][4];
#pragma unroll
  for (int mt = 0; mt < 2; mt++)
#pragma unroll
    for (int kc = 0; kc < 4; kc++)
      af[mt][kc] =
          *(bf16x8*)&Xl[(wv * 32 + mt * 16 + lm) * 136 + kc * 32 + quad * 8];
#pragma unroll
  for (int mt = 0; mt < 2; mt++)
#pragma unroll
    for (int nt = 0; nt < 8; nt++) acc[mt][nt] = (floatx4){0.f, 0.f, 0.f, 0.f};
#pragma unroll
  for (int kc = 0; kc < 4; kc++) {
#pragma unroll
    for (int nt = 0; nt < 8; nt++) {
      bf16x8 b = *(bf16x8*)&Wl[(nt * 16 + lm) * 136 + kc * 32 + quad * 8];
      acc[0][nt] =
          __builtin_amdgcn_mfma_f32_16x16x32_bf16(af[0][kc], b, acc[0][nt], 0, 0, 0);
      acc[1][nt] =
          __builtin_amdgcn_mfma_f32_16x16x32_bf16(af[1][kc], b, acc[1][nt], 0, 0, 0);
    }
  }
}
__device__ __forceinline__ void store_sl2(short* Sl, const floatx4 acc[2][8],
                                          const float* __restrict__ bias,
                                          int wv, int lm, int quad) {
#pragma unroll
  for (int mt = 0; mt < 2; mt++)
#pragma unroll
    for (int nt = 0; nt < 8; nt++) {
      int col = nt * 16 + lm;
      float bn = bias[col];
#pragma unroll
      for (int r = 0; r < 4; r++)
        Sl[(wv * 32 + mt * 16 + quad * 4 + r) * 136 + col] =
            f2bf(acc[mt][nt][r] + bn);
    }
}
// 128 rows: thread -> row tid>>1, col-half tid&1 (2 heads). wave-local rows.
__device__ __forceinline__ void write_hs2(const short* Sl,
                                          short* __restrict__ out, int rb,
                                          int nshift, int tid) {
  int rr = tid >> 1, half = tid & 1;
  int r = rb + rr;
  int bb = r >> nshift, nn = r & ((1 << nshift) - 1);
#pragma unroll
  for (int j2 = 0; j2 < 2; j2++) {
    int hh = half * 2 + j2;
    size_t o = (((size_t)(bb * NH + hh) << nshift) + nn) * 32;
#pragma unroll
    for (int j = 0; j < 4; j++)
      *(int4*)&out[o + j * 8] = *(int4*)&Sl[rr * 136 + hh * 32 + j * 8];
  }
}

// ---------------------------------------------------------------------------
// Kernel: merged weight-prep (blocks 0..23) + stable-order scan (blocks 24..39)
// ---------------------------------------------------------------------------
__global__ __launch_bounds__(1024) void prep_build_kernel(
    const float* __restrict__ q0w, const float* __restrict__ k0w,
    const float* __restrict__ v0w, const float* __restrict__ o0w,
    const float* __restrict__ q1w, const float* __restrict__ k1w,
    const float* __restrict__ v1w, const float* __restrict__ o1w,
    short* __restrict__ Wt,
    const float* __restrict__ mask, int* __restrict__ order,
    float* __restrict__ mk_out, float* __restrict__ mk_out2) {
  __shared__ float Tl[128 * 132];
  __shared__ int wsums[16];
  __shared__ int s_total_ones;
  __shared__ int s_chunk_ones;
  __shared__ int s_ones_base;
  __shared__ int s_zeros_base;
  int tid = threadIdx.x;

  if (blockIdx.x < 24) {
    int id = blockIdx.x, l = id >> 3, wi = id & 7;
    const float* s;
    switch (wi) {
      case 0: s = q0w; break; case 1: s = k0w; break;
      case 2: s = v0w; break; case 3: s = o0w; break;
      case 4: s = q1w; break; case 5: s = k1w; break;
      case 6: s = v1w; break; default: s = o1w; break;
    }
    s += (size_t)l * 16384;
    for (int i = tid * 4; i < 16384; i += 4096) {
      int k = i >> 7, n = i & 127;
      float4 x = *(const float4*)&s[i];
      Tl[k * 132 + n + 0] = x.x; Tl[k * 132 + n + 1] = x.y;
      Tl[k * 132 + n + 2] = x.z; Tl[k * 132 + n + 3] = x.w;
    }
    __syncthreads();
    short* dst = Wt + (size_t)id * 16384;
    int n = tid >> 3, k0 = (tid & 7) * 16;
    for (int jc = 0; jc < 2; jc++) {
      short8v t;
#pragma unroll
      for (int j = 0; j < 8; j++) t[j] = f2bf(Tl[(k0 + jc * 8 + j) * 132 + n]);
      *(short8v*)&dst[n * 128 + k0 + jc * 8] = t;
    }
    return;
  }

  int b = blockIdx.x - 24;
  const float* m = mask + (size_t)b * LDFLAT;
  int lane = tid & 63, w = tid >> 6;

  int cnt = 0;
  for (int j = tid; j < LDFLAT; j += 1024) cnt += (m[j] > 0.f) ? 1 : 0;
  for (int off = 32; off > 0; off >>= 1) cnt += __shfl_xor(cnt, off);
  if (lane == 0) wsums[w] = cnt;
  __syncthreads();
  if (tid == 0) {
    int t = 0;
    for (int i = 0; i < 16; i++) t += wsums[i];
    s_total_ones = t; s_ones_base = 0; s_zeros_base = 0;
  }
  __syncthreads();
  int total_ones = s_total_ones;

  for (int c0 = 0; c0 < LDFLAT; c0 += 1024) {
    __syncthreads();
    int j = c0 + tid;
    bool valid = (j < LDFLAT);
    float mv = valid ? m[j] : 0.f;
    int one = (valid && mv > 0.f) ? 1 : 0;
    int v = one;
    for (int off = 1; off < 64; off <<= 1) {
      int t = __shfl_up(v, (unsigned)off);
      if (lane >= off) v += t;
    }
    if (lane == 63) wsums[w] = v;
    __syncthreads();
    if (tid == 0) {
      int run = 0;
      for (int i = 0; i < 16; i++) { int t = wsums[i]; wsums[i] = run; run += t; }
      s_chunk_ones = run;
    }
    __syncthreads();
    int ones_before = (v - one) + wsums[w];
    int ob = s_ones_base, zb = s_zeros_base, chunk_ones = s_chunk_ones;
    int rem = LDFLAT - c0;
    int chunk_valid = rem < 1024 ? rem : 1024;
    int valid_before = tid < rem ? tid : rem;
    if (valid) {
      int pos = one ? (ob + ones_before)
                    : (total_ones + zb + (valid_before - ones_before));
      if (pos < OBS) {
        order[b * OBS + pos] = j;
        mk_out[b * OBS + pos] = mv;
        mk_out2[b * OBS + pos] = mv;
      }
    }
    __syncthreads();
    if (tid == 0) {
      s_ones_base = ob + chunk_ones;
      s_zeros_base = zb + (chunk_valid - chunk_ones);
    }
  }
}

// ---------------------------------------------------------------------------
// Kernel: fusedA — embed (layer-0 Z) + K0/V0/Q1 projections, 128 rows/block
// (blocks 0..511) + ind-point Q projections (blocks 512..517).
// ---------------------------------------------------------------------------
__global__ __launch_bounds__(256) void fusedA_kernel(
    const int* __restrict__ order, const float* __restrict__ mk_g,
    const float* __restrict__ cx, const float* __restrict__ value,
    const float* __restrict__ iff_w, const float* __restrict__ iff_b,
    float* __restrict__ Z,
    const short* __restrict__ Wk, const float* __restrict__ kbias,
    short* __restrict__ Kb,
    const short* __restrict__ Wv, const float* __restrict__ vbias,
    short* __restrict__ Vb,
    const short* __restrict__ Wq, const float* __restrict__ qbias,
    short* __restrict__ Qb,
    const float* __restrict__ indp, const short* __restrict__ WtAll,
    const float* __restrict__ q0b_all, short* __restrict__ qh_b) {
  __shared__ __align__(16) short Xl[128 * 136];
  __shared__ __align__(16) short Wl[128 * 136];
  __shared__ int   rdd[128];
  __shared__ float rdt[128], rdu[128], rdm[128];
  int tid = threadIdx.x;
  int wv = tid >> 6, lane = tid & 63, lm = lane & 15, quad = lane >> 4;

  if (blockIdx.x >= 512) {
    // ---- qh_proj path (64 rows) ----
    int id = blockIdx.x - 512;
    int l = id >> 1, rbq = (id & 1) * 64;
    const float* X = indp + (size_t)l * 16384 + (size_t)rbq * 128;
    const short* W = WtAll + (size_t)(l * 8) * 16384;
    const float* bias = q0b_all + (size_t)l * 128;
    short* out = qh_b + (size_t)l * 16384;
    for (int i = tid * 4; i < 64 * 128; i += 1024) {
      int rr = i >> 7, c = i & 127;
      float4 x = *(const float4*)&X[i];
      *(short4*)&Xl[rr * 136 + c] =
          make_short4(f2bf(x.x), f2bf(x.y), f2bf(x.z), f2bf(x.w));
    }
    stage_w(Wl, W, tid);
    __syncthreads();
    bf16x8 af[4];
    load_af(Xl, wv, lm, quad, af);
    floatx4 acc[8];
    gemm8(Wl, af, lm, quad, acc);
    __syncthreads();
    store_sl(Wl, acc, bias, wv, lm, quad);
    __syncthreads();
    write_hs(Wl, out, rbq, 7, tid);
    return;
  }

  int rb = blockIdx.x * 128;
  if (tid < 128) {
    int idx = rb + tid;
    int b = idx >> 12;
    int j = order[idx];
    int l = j / DIM;
    rdd[tid] = j - l * DIM;
    rdt[tid] = cx[b * SEQL + l];
    rdu[tid] = value[(size_t)b * LDFLAT + j];
    rdm[tid] = mk_g[idx];
  }
  stage_w(Wl, Wk, tid);
  __syncthreads();   // B1
  for (int i = tid * 4; i < 128 * 128; i += 1024) {
    int rr = i >> 7, k = i & 127;
    float4 w0 = *(const float4*)&iff_w[rdd[rr] * DK + k];
    float4 w1 = *(const float4*)&iff_w[41 * DK + k];
    float4 w2 = *(const float4*)&iff_w[42 * DK + k];
    float4 b4 = *(const float4*)&iff_b[k];
    float t = rdt[rr], u = rdu[rr], mkv = rdm[rr];
    float4 z;
    z.x = fmaxf(w0.x + t * w1.x + u * w2.x + b4.x, 0.f) * mkv;
    z.y = fmaxf(w0.y + t * w1.y + u * w2.y + b4.y, 0.f) * mkv;
    z.z = fmaxf(w0.z + t * w1.z + u * w2.z + b4.z, 0.f) * mkv;
    z.w = fmaxf(w0.w + t * w1.w + u * w2.w + b4.w, 0.f) * mkv;
    *(float4*)&Z[(size_t)(rb + rr) * DK + k] = z;
    *(short4*)&Xl[rr * 136 + k] =
        make_short4(f2bf(z.x), f2bf(z.y), f2bf(z.z), f2bf(z.w));
  }
  __syncthreads();   // B2
  floatx4 acc[2][8];
  gemm16(Wl, Xl, wv, lm, quad, acc);
  __syncthreads();   // B3
  store_sl2(Wl, acc, kbias, wv, lm, quad);
  write_hs2(Wl, Kb, rb, 12, tid);        // wave-local rows
  __syncthreads();   // B4
  stage_w(Wl, Wv, tid);
  __syncthreads();   // B5
  gemm16(Wl, Xl, wv, lm, quad, acc);
  __syncthreads();   // B6
  store_sl2(Wl, acc, vbias, wv, lm, quad);
  write_hs2(Wl, Vb, rb, 12, tid);
  __syncthreads();   // B7
  stage_w(Wl, Wq, tid);
  __syncthreads();   // B8
  gemm16(Wl, Xl, wv, lm, quad, acc);
  __syncthreads();   // B9
  store_sl2(Wl, acc, qbias, wv, lm, quad);
  write_hs2(Wl, Qb, rb, 12, tid);
}

// ---------------------------------------------------------------------------
// Kernel: MAB1 attention (bf16), flash over 8 key splits. grid (64, 8).
// ---------------------------------------------------------------------------
__global__ __launch_bounds__(256) void attn1_kernel(
    const short* __restrict__ Qh,   // (NH,128,32) bf16, layer base
    const short* __restrict__ Kh, const short* __restrict__ Vh,
    const float* __restrict__ mk,
    float* __restrict__ Opart, float* __restrict__ mpart,
    float* __restrict__ lpart) {
  __shared__ __align__(16) short Ql[128 * 40];
  __shared__ __align__(16) short Kc[64 * 40];
  __shared__ __align__(16) short Vtc[32 * 72];
  __shared__ __align__(16) short Pl[128 * 72];
  __shared__ float mkc[64];
  int bh = blockIdx.x;
  int b = bh >> 2, h = bh & 3;
  int ks = blockIdx.y;
  int tid = threadIdx.x;
  int wv = tid >> 6, lane = tid & 63, lm = lane & 15, quad = lane >> 4;

  const short* qbg = Qh + (size_t)h * 128 * 32;
  for (int i = tid * 8; i < 128 * 32; i += 2048) {
    int r = i >> 5, c = i & 31;
    *(int4*)&Ql[r * 40 + c] = *(const int4*)&qbg[i];
  }
  __syncthreads();
  bf16x8 aq[2];
  aq[0] = *(bf16x8*)&Ql[(wv * 32 + lm) * 40 + quad * 8];
  aq[1] = *(bf16x8*)&Ql[(wv * 32 + 16 + lm) * 40 + quad * 8];

  float m_i[2][4], l_i[2][4];
  floatx4 oacc[2][2];
#pragma unroll
  for (int mt = 0; mt < 2; mt++) {
#pragma unroll
    for (int r = 0; r < 4; r++) { m_i[mt][r] = -1e30f; l_i[mt][r] = 0.f; }
    oacc[mt][0] = (floatx4){0.f, 0.f, 0.f, 0.f};
    oacc[mt][1] = (floatx4){0.f, 0.f, 0.f, 0.f};
  }
  const float scale = 0.08838834764831845f;
  const short* kbase = Kh + ((size_t)bh * OBS + ks * 512) * 32;
  const short* vbase = Vh + ((size_t)bh * OBS + ks * 512) * 32;
  const float* mkb = mk + (size_t)b * OBS + ks * 512;

  for (int ch = 0; ch < 8; ch++) {
    __syncthreads();
    {
      int i = tid * 8;
      int r = i >> 5, c = i & 31;
      *(int4*)&Kc[r * 40 + c] = *(const int4*)&kbase[ch * 2048 + i];
      int4 vv4 = *(const int4*)&vbase[ch * 2048 + i];
      short* vv = (short*)&vv4;
#pragma unroll
      for (int j = 0; j < 8; j++) Vtc[(c + j) * 72 + r] = vv[j];
    }
    if (tid < 64) mkc[tid] = mkb[ch * 64 + tid];
    __syncthreads();

    floatx4 sf[2][4];
#pragma unroll
    for (int nt = 0; nt < 4; nt++) {
      bf16x8 bfrag = *(bf16x8*)&Kc[(nt * 16 + lm) * 40 + quad * 8];
      floatx4 z = {0.f, 0.f, 0.f, 0.f};
      sf[0][nt] = __builtin_amdgcn_mfma_f32_16x16x32_bf16(aq[0], bfrag, z, 0, 0, 0);
      sf[1][nt] = __builtin_amdgcn_mfma_f32_16x16x32_bf16(aq[1], bfrag, z, 0, 0, 0);
    }
#pragma unroll
    for (int nt = 0; nt < 4; nt++) {
      float mkv = mkc[nt * 16 + lm];
      bool ok = mkv > 0.f;
#pragma unroll
      for (int mt = 0; mt < 2; mt++)
#pragma unroll
        for (int r = 0; r < 4; r++)
          sf[mt][nt][r] = ok ? sf[mt][nt][r] * scale : -1e10f;
    }
#pragma unroll
    for (int mt = 0; mt < 2; mt++) {
#pragma unroll
      for (int r = 0; r < 4; r++) {
        float mx = fmaxf(fmaxf(sf[mt][0][r], sf[mt][1][r]),
                         fmaxf(sf[mt][2][r], sf[mt][3][r]));
        mx = fmaxf(mx, __shfl_xor(mx, 1));
        mx = fmaxf(mx, __shfl_xor(mx, 2));
        mx = fmaxf(mx, __shfl_xor(mx, 4));
        mx = fmaxf(mx, __shfl_xor(mx, 8));
        float mn = fmaxf(m_i[mt][r], mx);
        float al = __expf(m_i[mt][r] - mn);
        float ps = 0.f;
#pragma unroll
        for (int nt = 0; nt < 4; nt++) {
          float p = __expf(sf[mt][nt][r] - mn);
          sf[mt][nt][r] = p;
          ps += p;
        }
        ps += __shfl_xor(ps, 1);
        ps += __shfl_xor(ps, 2);
        ps += __shfl_xor(ps, 4);
        ps += __shfl_xor(ps, 8);
        l_i[mt][r] = l_i[mt][r] * al + ps;
        m_i[mt][r] = mn;
        oacc[mt][0] *= al;
        oacc[mt][1] *= al;
      }
    }
#pragma unroll
    for (int mt = 0; mt < 2; mt++)
#pragma unroll
      for (int nt = 0; nt < 4; nt++)
#pragma unroll
        for (int r = 0; r < 4; r++)
          Pl[(wv * 32 + mt * 16 + quad * 4 + r) * 72 + nt * 16 + lm] =
              f2bf(sf[mt][nt][r]);
#pragma unroll
    for (int kc = 0; kc < 2; kc++) {
      bf16x8 vf0 = *(bf16x8*)&Vtc[lm * 72 + kc * 32 + quad * 8];
      bf16x8 vf1 = *(bf16x8*)&Vtc[(16 + lm) * 72 + kc * 32 + quad * 8];
#pragma unroll
      for (int mt = 0; mt < 2; mt++) {
        bf16x8 pf = *(bf16x8*)&Pl[(wv * 32 + mt * 16 + lm) * 72 + kc * 32 + quad * 8];
        oacc[mt][0] = __builtin_amdgcn_mfma_f32_16x16x32_bf16(pf, vf0, oacc[mt][0], 0, 0, 0);
        oacc[mt][1] = __builtin_amdgcn_mfma_f32_16x16x32_bf16(pf, vf1, oacc[mt][1], 0, 0, 0);
      }
    }
  }
  float* ob = Opart + (size_t)(ks * 64 + bh) * 128 * 32;
#pragma unroll
  for (int mt = 0; mt < 2; mt++) {
#pragma unroll
    for (int r = 0; r < 4; r++) {
      int row = wv * 32 + mt * 16 + quad * 4 + r;
      ob[(size_t)row * 32 + lm] = oacc[mt][0][r];
      ob[(size_t)row * 32 + 16 + lm] = oacc[mt][1][r];
      if (lm == 0) {
        mpart[(size_t)(ks * 64 + bh) * 128 + row] = m_i[mt][r];
        lpart[(size_t)(ks * 64 + bh) * 128 + row] = l_i[mt][r];
      }
    }
  }
}

// ---------------------------------------------------------------------------
// Kernel: fusedB — attn1 combine + fc_o + K1/V1 projections. grid 32.
// ---------------------------------------------------------------------------
__global__ __launch_bounds__(256) void fusedB_kernel(
    const float* __restrict__ Opart, const float* __restrict__ mpart,
    const float* __restrict__ lpart, const short* __restrict__ qh,
    const short* __restrict__ Wo, const float* __restrict__ obias,
    const short* __restrict__ Wk, const float* __restrict__ kbias,
    const short* __restrict__ Wv, const float* __restrict__ vbias,
    short* __restrict__ khb, short* __restrict__ vhb) {
  __shared__ __align__(16) short Xl[64 * 136];
  __shared__ __align__(16) short Wl[128 * 136];
  int tid = threadIdx.x;
  int rb = blockIdx.x * 64;           // row in 2048 = b*128 + n
  int b = rb >> 7, n0 = rb & 127;
  {
    int rr = tid >> 2, hh = tid & 3;
    int n = n0 + rr;
    int bh = b * 4 + hh;
    float mv[8], lv[8], m = -1e30f;
#pragma unroll
    for (int s = 0; s < 8; s++) {
      mv[s] = mpart[(size_t)(s * 64 + bh) * 128 + n];
      lv[s] = lpart[(size_t)(s * 64 + bh) * 128 + n];
      m = fmaxf(m, mv[s]);
    }
    float l = 0.f;
    float oa[32];
#pragma unroll
    for (int d = 0; d < 32; d++) oa[d] = 0.f;
#pragma unroll
    for (int s = 0; s < 8; s++) {
      float w = __expf(mv[s] - m);
      l += lv[s] * w;
      const float* op = &Opart[((size_t)(s * 64 + bh) * 128 + n) * 32];
#pragma unroll
      for (int d4 = 0; d4 < 8; d4++) {
        float4 v = *(const float4*)&op[d4 * 4];
        oa[d4 * 4 + 0] += v.x * w; oa[d4 * 4 + 1] += v.y * w;
        oa[d4 * 4 + 2] += v.z * w; oa[d4 * 4 + 3] += v.w * w;
      }
    }
    float li = 1.f / l;
    const short* qp = &qh[((size_t)hh * 128 + n) * 32];
#pragma unroll
    for (int d = 0; d < 32; d++)
      Xl[rr * 136 + hh * 32 + d] = f2bf(bf2f(qp[d]) + oa[d] * li);
  }
  stage_w(Wl, Wo, tid);
  __syncthreads();
  int wv = tid >> 6, lane = tid & 63, lm = lane & 15, quad = lane >> 4;
  bf16x8 af[4];
  load_af(Xl, wv, lm, quad, af);
  floatx4 acc[8];
  gemm8(Wl, af, lm, quad, acc);
  __syncthreads();
  // H = O + relu(acc + bias) -> stage in Wl as bf16
#pragma unroll
  for (int nt = 0; nt < 8; nt++) {
    int col = nt * 16 + lm;
    float bn = obias[col];
#pragma unroll
    for (int r = 0; r < 4; r++) {
      int row = wv * 16 + quad * 4 + r;
      float ov = bf2f(Xl[row * 136 + col]);
      Wl[row * 136 + col] = f2bf(ov + fmaxf(acc[nt][r] + bn, 0.f));
    }
  }
  __syncthreads();
  // copy H into Xl
  for (int i = tid * 8; i < 64 * 128; i += 2048)
    *(int4*)&Xl[(i >> 7) * 136 + (i & 127)] = *(int4*)&Wl[(i >> 7) * 136 + (i & 127)];
  __syncthreads();
  load_af(Xl, wv, lm, quad, af);
  stage_w(Wl, Wk, tid);
  __syncthreads();
  gemm8(Wl, af, lm, quad, acc);
  __syncthreads();
  store_sl(Wl, acc, kbias, wv, lm, quad);
  __syncthreads();
  write_hs(Wl, khb, rb, 7, tid);
  __syncthreads();
  stage_w(Wl, Wv, tid);
  __syncthreads();
  gemm8(Wl, af, lm, quad, acc);
  __syncthreads();
  store_sl(Wl, acc, vbias, wv, lm, quad);
  __syncthreads();
  write_hs(Wl, vhb, rb, 7, tid);
}

// ---------------------------------------------------------------------------
// Kernel: MAB2 attention, register softmax. grid (64, 64). LDS ~42 KB.
// ---------------------------------------------------------------------------
__global__ __launch_bounds__(256) void attn2_kernel(
    const short* __restrict__ Qh, const short* __restrict__ Kh,
    const short* __restrict__ Vh, short* __restrict__ O) {
  __shared__ __align__(16) short Kl[128 * 40];
  __shared__ __align__(16) short Vt[32 * 136];
  __shared__ __align__(16) short Ql[64 * 40];
  __shared__ __align__(16) short Pl[64 * 136];
  int bh = blockIdx.x;
  int b = bh >> 2, h = bh & 3;
  int q0 = blockIdx.y * 64;
  int tid = threadIdx.x;
  int wv = tid >> 6, lane = tid & 63, lm = lane & 15, quad = lane >> 4;
  const short* kb = Kh + (size_t)bh * 128 * 32;
  const short* vb = Vh + (size_t)bh * 128 * 32;
  const short* qb = Qh + ((size_t)bh * OBS + q0) * 32;

  for (int i = tid * 8; i < 128 * 32; i += 2048) {
    int r = i >> 5, c = i & 31;
    *(int4*)&Kl[r * 40 + c] = *(const int4*)&kb[i];
  }
  for (int i = tid * 8; i < 64 * 32; i += 2048) {
    int r = i >> 5, c = i & 31;
    *(int4*)&Ql[r * 40 + c] = *(const int4*)&qb[i];
  }
  for (int i = tid * 8; i < 128 * 32; i += 2048) {
    int r = i >> 5, c = i & 31;
    int4 vv4 = *(const int4*)&vb[i];
    short* vv = (short*)&vv4;
#pragma unroll
    for (int j = 0; j < 8; j++) Vt[(c + j) * 136 + r] = vv[j];
  }
  __syncthreads();

  const float scale = 0.08838834764831845f;
  bf16x8 afrag = *(bf16x8*)&Ql[(wv * 16 + lm) * 40 + quad * 8];
  floatx4 sf[8];
#pragma unroll
  for (int nt = 0; nt < 8; nt++) {
    bf16x8 bfrag = *(bf16x8*)&Kl[(nt * 16 + lm) * 40 + quad * 8];
    floatx4 z = {0.f, 0.f, 0.f, 0.f};
    sf[nt] = __builtin_amdgcn_mfma_f32_16x16x32_bf16(afrag, bfrag, z, 0, 0, 0);
  }
#pragma unroll
  for (int nt = 0; nt < 8; nt++) sf[nt] *= scale;
  float linv[4];
#pragma unroll
  for (int r = 0; r < 4; r++) {
    float mx = sf[0][r];
#pragma unroll
    for (int nt = 1; nt < 8; nt++) mx = fmaxf(mx, sf[nt][r]);
    mx = fmaxf(mx, __shfl_xor(mx, 1));
    mx = fmaxf(mx, __shfl_xor(mx, 2));
    mx = fmaxf(mx, __shfl_xor(mx, 4));
    mx = fmaxf(mx, __shfl_xor(mx, 8));
    float sum = 0.f;
#pragma unroll
    for (int nt = 0; nt < 8; nt++) {
      float p = __expf(sf[nt][r] - mx);
      sf[nt][r] = p;
      sum += p;
    }
    sum += __shfl_xor(sum, 1);
    sum += __shfl_xor(sum, 2);
    sum += __shfl_xor(sum, 4);
    sum += __shfl_xor(sum, 8);
    linv[r] = 1.f / sum;
  }
#pragma unroll
  for (int nt = 0; nt < 8; nt++)
#pragma unroll
    for (int r = 0; r < 4; r++)
      Pl[(wv * 16 + quad * 4 + r) * 136 + nt * 16 + lm] = f2bf(sf[nt][r]);

  floatx4 oacc[2] = {{0.f, 0.f, 0.f, 0.f}, {0.f, 0.f, 0.f, 0.f}};
#pragma unroll
  for (int kc = 0; kc < 4; kc++) {
    bf16x8 pf = *(bf16x8*)&Pl[(wv * 16 + lm) * 136 + kc * 32 + quad * 8];
#pragma unroll
    for (int nt2 = 0; nt2 < 2; nt2++) {
      bf16x8 vf = *(bf16x8*)&Vt[(nt2 * 16 + lm) * 136 + kc * 32 + quad * 8];
      oacc[nt2] = __builtin_amdgcn_mfma_f32_16x16x32_bf16(pf, vf, oacc[nt2], 0, 0, 0);
    }
  }
  // stage O+Q residual in Pl rows (wave-local), then coalesced int4 store
  short* Ol = Pl;
#pragma unroll
  for (int nt2 = 0; nt2 < 2; nt2++) {
#pragma unroll
    for (int r = 0; r < 4; r++) {
      int qrow = wv * 16 + quad * 4 + r;
      float q = bf2f(Ql[qrow * 40 + nt2 * 16 + lm]);
      Ol[qrow * 136 + nt2 * 16 + lm] = f2bf(q + oacc[nt2][r] * linv[r]);
    }
  }
  int rr = tid >> 2, seg = tid & 3;      // wave-local Ol rows
  size_t o = ((size_t)b * OBS + q0 + rr) * 128 + h * 32 + seg * 8;
  *(int4*)&O[o] = *(int4*)&Ol[rr * 136 + seg * 8];
}

// ---------------------------------------------------------------------------
// Kernel: fusedC — fc_o + residual Z update + next layer's K0/V0/Q1.
// 128 rows/block, grid 512. Wk==null => last layer (no projections).
// ---------------------------------------------------------------------------
__global__ __launch_bounds__(256) void fusedC_kernel(
    const short* __restrict__ Ob, const short* __restrict__ Wo,
    const float* __restrict__ obias, const float* __restrict__ mk,
    const float* __restrict__ Zin, float* __restrict__ Zout,
    const short* __restrict__ Wk, const float* __restrict__ kbias,
    short* __restrict__ Kb,
    const short* __restrict__ Wv, const float* __restrict__ vbias,
    short* __restrict__ Vb,
    const short* __restrict__ Wq, const float* __restrict__ qbias,
    short* __restrict__ Qb) {
  __shared__ __align__(16) short Xl[128 * 136];
  __shared__ __align__(16) short Wl[128 * 136];
  int tid = threadIdx.x;
  int rb = blockIdx.x * 128;
  int wv = tid >> 6, lane = tid & 63, lm = lane & 15, quad = lane >> 4;
  for (int i = tid * 8; i < 128 * 128; i += 2048) {
    int rr = i >> 7, c = i & 127;
    *(int4*)&Xl[rr * 136 + c] = *(const int4*)&Ob[(size_t)(rb + rr) * 128 + c];
  }
  stage_w(Wl, Wo, tid);
  __syncthreads();   // B1
  floatx4 acc[2][8];
  gemm16(Wl, Xl, wv, lm, quad, acc);
  __syncthreads();   // B2: Wl free -> Fl (64-row fp32 buffer, reused per mt)
  float* Fl = (float*)Wl;   // 64 x 132 fp32
#pragma unroll
  for (int mt = 0; mt < 2; mt++) {
    // fill (wave-local Fl rows 16wv..16wv+15)
    float mkv[4];
#pragma unroll
    for (int r = 0; r < 4; r++)
      mkv[r] = mk[rb + wv * 32 + mt * 16 + quad * 4 + r];
#pragma unroll
    for (int nt = 0; nt < 8; nt++) {
      int col = nt * 16 + lm;
      float bn = obias[col];
#pragma unroll
      for (int r = 0; r < 4; r++) {
        int lrow = wv * 16 + quad * 4 + r;
        int xrow = wv * 32 + mt * 16 + quad * 4 + r;
        int gr = rb + xrow;
        float ov = bf2f(Xl[xrow * 136 + col]);
        float f = ov + fmaxf(acc[mt][nt][r] + bn, 0.f);
        Fl[lrow * 132 + col] = Zin[(size_t)gr * 128 + col] + f * mkv[r];
      }
    }
    // vector pass (wave-local): Zout float4 + Xl bf16
    {
      int rr = tid >> 2, seg = tid & 3;
      int xrow = (rr >> 4) * 32 + mt * 16 + (rr & 15);
      int gr = rb + xrow;
#pragma unroll
      for (int j = 0; j < 8; j++) {
        float4 f = *(float4*)&Fl[rr * 132 + seg * 32 + j * 4];
        *(float4*)&Zout[(size_t)gr * 128 + seg * 32 + j * 4] = f;
        if (Wk)
          *(short4*)&Xl[xrow * 136 + seg * 32 + j * 4] =
              make_short4(f2bf(f.x), f2bf(f.y), f2bf(f.z), f2bf(f.w));
      }
    }
  }
  if (Wk == nullptr) return;
  __syncthreads();   // B3: all waves done with Fl
  stage_w(Wl, Wk, tid);
  __syncthreads();   // B4
  gemm16(Wl, Xl, wv, lm, quad, acc);
  __syncthreads();   // B5
  store_sl2(Wl, acc, kbias, wv, lm, quad);
  write_hs2(Wl, Kb, rb, 12, tid);        // wave-local rows
  __syncthreads();   // B6
  stage_w(Wl, Wv, tid);
  __syncthreads();   // B7
  gemm16(Wl, Xl, wv, lm, quad, acc);
  __syncthreads();   // B8
  store_sl2(Wl, acc, vbias, wv, lm, quad);
  write_hs2(Wl, Vb, rb, 12, tid);
  __syncthreads();   // B9
  stage_w(Wl, Wq, tid);
  __syncthreads();   // B10
  gemm16(Wl, Xl, wv, lm, quad, acc);
  __syncthreads();   // B11
  store_sl2(Wl, acc, qbias, wv, lm, quad);
  write_hs2(Wl, Qb, rb, 12, tid);
}

// ---------------------------------------------------------------------------
extern "C" void kernel_launch(void* const* d_in, const int* in_sizes, int n_in,
                              void* d_out, int out_size, void* d_ws,
                              size_t ws_size, hipStream_t stream) {
  const float* cx    = (const float*)d_in[0];
  const float* value = (const float*)d_in[1];
  const float* mask  = (const float*)d_in[2];
  const float* iff_w = (const float*)d_in[4];
  const float* iff_b = (const float*)d_in[5];
  const float* indp  = (const float*)d_in[6];
  const float* q0w = (const float*)d_in[7];  const float* q0b = (const float*)d_in[8];
  const float* k0w = (const float*)d_in[9];  const float* k0b = (const float*)d_in[10];
  const float* v0w = (const float*)d_in[11]; const float* v0b = (const float*)d_in[12];
  const float* o0w = (const float*)d_in[13]; const float* o0b = (const float*)d_in[14];
  const float* q1w = (const float*)d_in[15]; const float* q1b = (const float*)d_in[16];
  const float* k1w = (const float*)d_in[17]; const float* k1b = (const float*)d_in[18];
  const float* v1w = (const float*)d_in[19]; const float* v1b = (const float*)d_in[20];
  const float* o1w = (const float*)d_in[21]; const float* o1b = (const float*)d_in[22];

  char* ws = (char*)d_ws;
  short* Wt    = (short*)ws;  ws += (size_t)24 * 16384 * 2;
  int*   order = (int*)ws;    ws += (size_t)NBATCH * OBS * 4;
  float* mk_g  = (float*)ws;  ws += (size_t)NBATCH * OBS * 4;
  float* Z     = (float*)ws;  ws += (size_t)NBATCH * OBS * DK * 4;
  short* Qb    = (short*)ws;  ws += (size_t)NBATCH * OBS * DK * 2;
  short* Kb    = (short*)ws;  ws += (size_t)NBATCH * OBS * DK * 2;
  short* Vb    = (short*)ws;  ws += (size_t)NBATCH * OBS * DK * 2;
  short* Ob    = (short*)ws;  ws += (size_t)NBATCH * OBS * DK * 2;
  short* qh_b  = (short*)ws;  ws += (size_t)3 * 128 * DK * 2;
  short* khb   = (short*)ws;  ws += (size_t)NBATCH * NH * 128 * DH * 2;
  short* vhb   = (short*)ws;  ws += (size_t)NBATCH * NH * 128 * DH * 2;
  float* Opart = (float*)ws;  ws += (size_t)8 * 64 * 128 * 32 * 4;
  float* mpart = (float*)ws;  ws += (size_t)8 * 64 * 128 * 4;
  float* lpart = (float*)ws;  ws += (size_t)8 * 64 * 128 * 4;

  float* outZ  = (float*)d_out;
  float* outMk = outZ + (size_t)NBATCH * OBS * DK;

  prep_build_kernel<<<40, 1024, 0, stream>>>(q0w, k0w, v0w, o0w, q1w, k1w,
                                             v1w, o1w, Wt, mask, order, mk_g,
                                             outMk);

  const short* W[3][8];
  for (int l = 0; l < 3; l++)
    for (int wi = 0; wi < 8; wi++) W[l][wi] = Wt + (size_t)(l * 8 + wi) * 16384;

  fusedA_kernel<<<518, 256, 0, stream>>>(
      order, mk_g, cx, value, iff_w, iff_b, Z,
      W[0][1], k0b, Kb, W[0][2], v0b, Vb, W[0][4], q1b, Qb,
      indp, Wt, q0b, qh_b);

  for (int l = 0; l < 3; l++) {
    attn1_kernel<<<dim3(64, 8), 256, 0, stream>>>(
        qh_b + (size_t)l * 16384, Kb, Vb, mk_g, Opart, mpart, lpart);
    fusedB_kernel<<<32, 256, 0, stream>>>(
        Opart, mpart, lpart, qh_b + (size_t)l * 16384,
        W[l][3], o0b + (size_t)l * 128,
        W[l][5], k1b + (size_t)l * 128,
        W[l][6], v1b + (size_t)l * 128, khb, vhb);
    attn2_kernel<<<dim3(64, 64), 256, 0, stream>>>(Qb, khb, vhb, Ob);
    if (l < 2) {
      fusedC_kernel<<<512, 256, 0, stream>>>(
          Ob, W[l][7], o1b + (size_t)l * 128, mk_g, Z, Z,
          W[l + 1][1], k0b + (size_t)(l + 1) * 128, Kb,
          W[l + 1][2], v0b + (size_t)(l + 1) * 128, Vb,
          W[l + 1][4], q1b + (size_t)(l + 1) * 128, Qb);
    } else {
      fusedC_kernel<<<512, 256, 0, stream>>>(
          Ob, W[l][7], o1b + (size_t)l * 128, mk_g, Z, outZ,
          nullptr, nullptr, nullptr, nullptr, nullptr, nullptr,
          nullptr, nullptr, nullptr);
    }
  }
}

// Round 9
// 507.702 us; speedup vs baseline: 1.0672x; 1.0672x over previous
//
#include <hip/hip_runtime.h>
#include <math.h>

#define NBATCH 16
#define SEQL   512
#define DIM    41
#define LDFLAT (SEQL*DIM)   // 20992
#define OBS    4096
#define DK     128
#define NH     4
#define DH     32

typedef short bf16x8 __attribute__((ext_vector_type(8)));
typedef short short8v __attribute__((ext_vector_type(8)));
typedef float floatx4 __attribute__((ext_vector_type(4)));

__device__ __forceinline__ short f2bf(float f) {
  union { float f; unsigned u; } v;
  v.f = f;
  unsigned r = (v.u + 0x7fffu + ((v.u >> 16) & 1u)) >> 16;
  return (short)r;
}
__device__ __forceinline__ float bf2f(short s) {
  union { unsigned u; float f; } v;
  v.u = ((unsigned)(unsigned short)s) << 16;
  return v.f;
}

// ---- shared GEMM building blocks (64 rows x 128 cols, K=128) ----
// R5/R6 lesson: NO register weight-prefetch (vmcnt is ordered; commit-wait
// after epilogue stores parks the block). R8 lesson: keep 64-row blocks
// (52KB LDS, 3 blocks/CU) — 128-row halves occupancy and regresses.
// R9: stage GEMM results in Xl (dead after load_af caches A-fragments in
// regs) — deletes the 2 barriers/GEMM that sequenced result staging vs Wl.
__device__ __forceinline__ void stage_w(short* Wl, const short* __restrict__ Wt,
                                        int tid) {
#pragma unroll
  for (int i = tid * 8; i < 128 * 128; i += 2048)
    *(int4*)&Wl[(i >> 7) * 136 + (i & 127)] = *(const int4*)&Wt[i];
}
__device__ __forceinline__ void load_af(const short* Xl, int wv, int lm,
                                        int quad, bf16x8 af[4]) {
#pragma unroll
  for (int kc = 0; kc < 4; kc++)
    af[kc] = *(bf16x8*)&Xl[(wv * 16 + lm) * 136 + kc * 32 + quad * 8];
}
__device__ __forceinline__ void gemm8(const short* Wl, const bf16x8 af[4],
                                      int lm, int quad, floatx4 acc[8]) {
#pragma unroll
  for (int nt = 0; nt < 8; nt++) acc[nt] = (floatx4){0.f, 0.f, 0.f, 0.f};
#pragma unroll
  for (int kc = 0; kc < 4; kc++) {
    bf16x8 a = af[kc];
#pragma unroll
    for (int nt = 0; nt < 8; nt++) {
      bf16x8 b = *(bf16x8*)&Wl[(nt * 16 + lm) * 136 + kc * 32 + quad * 8];
      acc[nt] = __builtin_amdgcn_mfma_f32_16x16x32_bf16(a, b, acc[nt], 0, 0, 0);
    }
  }
}
// stage bias-added bf16 result (wave-local rows)
__device__ __forceinline__ void store_sl(short* Sl, const floatx4 acc[8],
                                         const float* __restrict__ bias,
                                         int wv, int lm, int quad) {
#pragma unroll
  for (int nt = 0; nt < 8; nt++) {
    int col = nt * 16 + lm;
    float bn = bias[col];
#pragma unroll
    for (int r = 0; r < 4; r++)
      Sl[(wv * 16 + quad * 4 + r) * 136 + col] = f2bf(acc[nt][r] + bn);
  }
}
// write Sl rows rb..rb+63 to head-split out (reads wave-local Sl rows)
__device__ __forceinline__ void write_hs(const short* Sl,
                                         short* __restrict__ out, int rb,
                                         int nshift, int tid) {
  int rr = tid >> 2, hh = tid & 3;
  int r = rb + rr;
  int bb = r >> nshift, nn = r & ((1 << nshift) - 1);
  size_t o = (((size_t)(bb * NH + hh) << nshift) + nn) * 32;
#pragma unroll
  for (int j = 0; j < 4; j++)
    *(int4*)&out[o + j * 8] = *(int4*)&Sl[rr * 136 + hh * 32 + j * 8];
}

// ---------------------------------------------------------------------------
// Kernel: merged weight-prep (blocks 0..23) + stable-order scan (blocks 24..39)
// ---------------------------------------------------------------------------
__global__ __launch_bounds__(1024) void prep_build_kernel(
    const float* __restrict__ q0w, const float* __restrict__ k0w,
    const float* __restrict__ v0w, const float* __restrict__ o0w,
    const float* __restrict__ q1w, const float* __restrict__ k1w,
    const float* __restrict__ v1w, const float* __restrict__ o1w,
    short* __restrict__ Wt,
    const float* __restrict__ mask, int* __restrict__ order,
    float* __restrict__ mk_out, float* __restrict__ mk_out2) {
  __shared__ float Tl[128 * 132];
  __shared__ int wsums[16];
  __shared__ int s_total_ones;
  __shared__ int s_chunk_ones;
  __shared__ int s_ones_base;
  __shared__ int s_zeros_base;
  int tid = threadIdx.x;

  if (blockIdx.x < 24) {
    int id = blockIdx.x, l = id >> 3, wi = id & 7;
    const float* s;
    switch (wi) {
      case 0: s = q0w; break; case 1: s = k0w; break;
      case 2: s = v0w; break; case 3: s = o0w; break;
      case 4: s = q1w; break; case 5: s = k1w; break;
      case 6: s = v1w; break; default: s = o1w; break;
    }
    s += (size_t)l * 16384;
    for (int i = tid * 4; i < 16384; i += 4096) {
      int k = i >> 7, n = i & 127;
      float4 x = *(const float4*)&s[i];
      Tl[k * 132 + n + 0] = x.x; Tl[k * 132 + n + 1] = x.y;
      Tl[k * 132 + n + 2] = x.z; Tl[k * 132 + n + 3] = x.w;
    }
    __syncthreads();
    short* dst = Wt + (size_t)id * 16384;
    int n = tid >> 3, k0 = (tid & 7) * 16;
    for (int jc = 0; jc < 2; jc++) {
      short8v t;
#pragma unroll
      for (int j = 0; j < 8; j++) t[j] = f2bf(Tl[(k0 + jc * 8 + j) * 132 + n]);
      *(short8v*)&dst[n * 128 + k0 + jc * 8] = t;
    }
    return;
  }

  int b = blockIdx.x - 24;
  const float* m = mask + (size_t)b * LDFLAT;
  int lane = tid & 63, w = tid >> 6;

  int cnt = 0;
  for (int j = tid; j < LDFLAT; j += 1024) cnt += (m[j] > 0.f) ? 1 : 0;
  for (int off = 32; off > 0; off >>= 1) cnt += __shfl_xor(cnt, off);
  if (lane == 0) wsums[w] = cnt;
  __syncthreads();
  if (tid == 0) {
    int t = 0;
    for (int i = 0; i < 16; i++) t += wsums[i];
    s_total_ones = t; s_ones_base = 0; s_zeros_base = 0;
  }
  __syncthreads();
  int total_ones = s_total_ones;

  for (int c0 = 0; c0 < LDFLAT; c0 += 1024) {
    __syncthreads();
    int j = c0 + tid;
    bool valid = (j < LDFLAT);
    float mv = valid ? m[j] : 0.f;
    int one = (valid && mv > 0.f) ? 1 : 0;
    int v = one;
    for (int off = 1; off < 64; off <<= 1) {
      int t = __shfl_up(v, (unsigned)off);
      if (lane >= off) v += t;
    }
    if (lane == 63) wsums[w] = v;
    __syncthreads();
    if (tid == 0) {
      int run = 0;
      for (int i = 0; i < 16; i++) { int t = wsums[i]; wsums[i] = run; run += t; }
      s_chunk_ones = run;
    }
    __syncthreads();
    int ones_before = (v - one) + wsums[w];
    int ob = s_ones_base, zb = s_zeros_base, chunk_ones = s_chunk_ones;
    int rem = LDFLAT - c0;
    int chunk_valid = rem < 1024 ? rem : 1024;
    int valid_before = tid < rem ? tid : rem;
    if (valid) {
      int pos = one ? (ob + ones_before)
                    : (total_ones + zb + (valid_before - ones_before));
      if (pos < OBS) {
        order[b * OBS + pos] = j;
        mk_out[b * OBS + pos] = mv;
        mk_out2[b * OBS + pos] = mv;
      }
    }
    __syncthreads();
    if (tid == 0) {
      s_ones_base = ob + chunk_ones;
      s_zeros_base = zb + (chunk_valid - chunk_ones);
    }
  }
}

// ---------------------------------------------------------------------------
// Kernel: fusedA — embed (layer-0 Z) + K0/V0/Q1 projections (blocks 0..1023)
//                + ind-point Q projections for all 3 layers (blocks 1024..1029)
// ---------------------------------------------------------------------------
__global__ __launch_bounds__(256) void fusedA_kernel(
    const int* __restrict__ order, const float* __restrict__ mk_g,
    const float* __restrict__ cx, const float* __restrict__ value,
    const float* __restrict__ iff_w, const float* __restrict__ iff_b,
    float* __restrict__ Z,
    const short* __restrict__ Wk, const float* __restrict__ kbias,
    short* __restrict__ Kb,
    const short* __restrict__ Wv, const float* __restrict__ vbias,
    short* __restrict__ Vb,
    const short* __restrict__ Wq, const float* __restrict__ qbias,
    short* __restrict__ Qb,
    const float* __restrict__ indp, const short* __restrict__ WtAll,
    const float* __restrict__ q0b_all, short* __restrict__ qh_b) {
  __shared__ __align__(16) short Xl[64 * 136];
  __shared__ __align__(16) short Wl[128 * 136];
  __shared__ int   rdd[64];
  __shared__ float rdt[64], rdu[64], rdm[64];
  int tid = threadIdx.x;
  int wv = tid >> 6, lane = tid & 63, lm = lane & 15, quad = lane >> 4;

  if (blockIdx.x >= 1024) {
    // ---- qh_proj path ----
    int id = blockIdx.x - 1024;
    int l = id >> 1, rbq = (id & 1) * 64;
    const float* X = indp + (size_t)l * 16384 + (size_t)rbq * 128;
    const short* W = WtAll + (size_t)(l * 8) * 16384;
    const float* bias = q0b_all + (size_t)l * 128;
    short* out = qh_b + (size_t)l * 16384;
    for (int i = tid * 4; i < 64 * 128; i += 1024) {
      int rr = i >> 7, c = i & 127;
      float4 x = *(const float4*)&X[i];
      *(short4*)&Xl[rr * 136 + c] =
          make_short4(f2bf(x.x), f2bf(x.y), f2bf(x.z), f2bf(x.w));
    }
    stage_w(Wl, W, tid);
    __syncthreads();
    bf16x8 af[4];
    load_af(Xl, wv, lm, quad, af);
    floatx4 acc[8];
    gemm8(Wl, af, lm, quad, acc);
    store_sl(Xl, acc, bias, wv, lm, quad);   // Xl dead (af in regs)
    write_hs(Xl, out, rbq, 7, tid);          // wave-local reads
    return;
  }

  int rb = blockIdx.x * 64;
  if (tid < 64) {
    int idx = rb + tid;
    int b = idx >> 12;
    int j = order[idx];
    int l = j / DIM;
    rdd[tid] = j - l * DIM;
    rdt[tid] = cx[b * SEQL + l];
    rdu[tid] = value[(size_t)b * LDFLAT + j];
    rdm[tid] = mk_g[idx];
  }
  stage_w(Wl, Wk, tid);
  __syncthreads();   // B1: gather regs + Wk staged
  for (int i = tid * 4; i < 64 * 128; i += 1024) {
    int rr = i >> 7, k = i & 127;
    float4 w0 = *(const float4*)&iff_w[rdd[rr] * DK + k];
    float4 w1 = *(const float4*)&iff_w[41 * DK + k];
    float4 w2 = *(const float4*)&iff_w[42 * DK + k];
    float4 b4 = *(const float4*)&iff_b[k];
    float t = rdt[rr], u = rdu[rr], mkv = rdm[rr];
    float4 z;
    z.x = fmaxf(w0.x + t * w1.x + u * w2.x + b4.x, 0.f) * mkv;
    z.y = fmaxf(w0.y + t * w1.y + u * w2.y + b4.y, 0.f) * mkv;
    z.z = fmaxf(w0.z + t * w1.z + u * w2.z + b4.z, 0.f) * mkv;
    z.w = fmaxf(w0.w + t * w1.w + u * w2.w + b4.w, 0.f) * mkv;
    *(float4*)&Z[(size_t)(rb + rr) * DK + k] = z;
    *(short4*)&Xl[rr * 136 + k] =
        make_short4(f2bf(z.x), f2bf(z.y), f2bf(z.z), f2bf(z.w));
  }
  __syncthreads();   // B2: Xl ready (cross-wave writes)
  bf16x8 af[4];
  load_af(Xl, wv, lm, quad, af);   // af cached for all 3 GEMMs; Xl now dead
  floatx4 acc[8];
  gemm8(Wl, af, lm, quad, acc);
  store_sl(Xl, acc, kbias, wv, lm, quad);
  write_hs(Xl, Kb, rb, 12, tid);
  __syncthreads();   // B3: all waves done reading Wl(Wk)
  stage_w(Wl, Wv, tid);
  __syncthreads();   // B4
  gemm8(Wl, af, lm, quad, acc);
  store_sl(Xl, acc, vbias, wv, lm, quad);
  write_hs(Xl, Vb, rb, 12, tid);
  __syncthreads();   // B5
  stage_w(Wl, Wq, tid);
  __syncthreads();   // B6
  gemm8(Wl, af, lm, quad, acc);
  store_sl(Xl, acc, qbias, wv, lm, quad);
  write_hs(Xl, Qb, rb, 12, tid);
}

// ---------------------------------------------------------------------------
// Kernel: MAB1 attention (bf16), flash over 8 key splits. grid (64, 8).
// ---------------------------------------------------------------------------
__global__ __launch_bounds__(256) void attn1_kernel(
    const short* __restrict__ Qh,   // (NH,128,32) bf16, layer base
    const short* __restrict__ Kh, const short* __restrict__ Vh,
    const float* __restrict__ mk,
    float* __restrict__ Opart, float* __restrict__ mpart,
    float* __restrict__ lpart) {
  __shared__ __align__(16) short Ql[128 * 40];
  __shared__ __align__(16) short Kc[64 * 40];
  __shared__ __align__(16) short Vtc[32 * 72];
  __shared__ __align__(16) short Pl[128 * 72];
  __shared__ float mkc[64];
  int bh = blockIdx.x;
  int b = bh >> 2, h = bh & 3;
  int ks = blockIdx.y;
  int tid = threadIdx.x;
  int wv = tid >> 6, lane = tid & 63, lm = lane & 15, quad = lane >> 4;

  const short* qbg = Qh + (size_t)h * 128 * 32;
  for (int i = tid * 8; i < 128 * 32; i += 2048) {
    int r = i >> 5, c = i & 31;
    *(int4*)&Ql[r * 40 + c] = *(const int4*)&qbg[i];
  }
  __syncthreads();
  bf16x8 aq[2];
  aq[0] = *(bf16x8*)&Ql[(wv * 32 + lm) * 40 + quad * 8];
  aq[1] = *(bf16x8*)&Ql[(wv * 32 + 16 + lm) * 40 + quad * 8];

  float m_i[2][4], l_i[2][4];
  floatx4 oacc[2][2];
#pragma unroll
  for (int mt = 0; mt < 2; mt++) {
#pragma unroll
    for (int r = 0; r < 4; r++) { m_i[mt][r] = -1e30f; l_i[mt][r] = 0.f; }
    oacc[mt][0] = (floatx4){0.f, 0.f, 0.f, 0.f};
    oacc[mt][1] = (floatx4){0.f, 0.f, 0.f, 0.f};
  }
  const float scale = 0.08838834764831845f;
  const short* kbase = Kh + ((size_t)bh * OBS + ks * 512) * 32;
  const short* vbase = Vh + ((size_t)bh * OBS + ks * 512) * 32;
  const float* mkb = mk + (size_t)b * OBS + ks * 512;

  for (int ch = 0; ch < 8; ch++) {
    __syncthreads();
    {
      int i = tid * 8;
      int r = i >> 5, c = i & 31;
      *(int4*)&Kc[r * 40 + c] = *(const int4*)&kbase[ch * 2048 + i];
      int4 vv4 = *(const int4*)&vbase[ch * 2048 + i];
      short* vv = (short*)&vv4;
#pragma unroll
      for (int j = 0; j < 8; j++) Vtc[(c + j) * 72 + r] = vv[j];
    }
    if (tid < 64) mkc[tid] = mkb[ch * 64 + tid];
    __syncthreads();

    floatx4 sf[2][4];
#pragma unroll
    for (int nt = 0; nt < 4; nt++) {
      bf16x8 bfrag = *(bf16x8*)&Kc[(nt * 16 + lm) * 40 + quad * 8];
      floatx4 z = {0.f, 0.f, 0.f, 0.f};
      sf[0][nt] = __builtin_amdgcn_mfma_f32_16x16x32_bf16(aq[0], bfrag, z, 0, 0, 0);
      sf[1][nt] = __builtin_amdgcn_mfma_f32_16x16x32_bf16(aq[1], bfrag, z, 0, 0, 0);
    }
#pragma unroll
    for (int nt = 0; nt < 4; nt++) {
      float mkv = mkc[nt * 16 + lm];
      bool ok = mkv > 0.f;
#pragma unroll
      for (int mt = 0; mt < 2; mt++)
#pragma unroll
        for (int r = 0; r < 4; r++)
          sf[mt][nt][r] = ok ? sf[mt][nt][r] * scale : -1e10f;
    }
#pragma unroll
    for (int mt = 0; mt < 2; mt++) {
#pragma unroll
      for (int r = 0; r < 4; r++) {
        float mx = fmaxf(fmaxf(sf[mt][0][r], sf[mt][1][r]),
                         fmaxf(sf[mt][2][r], sf[mt][3][r]));
        mx = fmaxf(mx, __shfl_xor(mx, 1));
        mx = fmaxf(mx, __shfl_xor(mx, 2));
        mx = fmaxf(mx, __shfl_xor(mx, 4));
        mx = fmaxf(mx, __shfl_xor(mx, 8));
        float mn = fmaxf(m_i[mt][r], mx);
        float al = __expf(m_i[mt][r] - mn);
        float ps = 0.f;
#pragma unroll
        for (int nt = 0; nt < 4; nt++) {
          float p = __expf(sf[mt][nt][r] - mn);
          sf[mt][nt][r] = p;
          ps += p;
        }
        ps += __shfl_xor(ps, 1);
        ps += __shfl_xor(ps, 2);
        ps += __shfl_xor(ps, 4);
        ps += __shfl_xor(ps, 8);
        l_i[mt][r] = l_i[mt][r] * al + ps;
        m_i[mt][r] = mn;
        oacc[mt][0] *= al;
        oacc[mt][1] *= al;
      }
    }
#pragma unroll
    for (int mt = 0; mt < 2; mt++)
#pragma unroll
      for (int nt = 0; nt < 4; nt++)
#pragma unroll
        for (int r = 0; r < 4; r++)
          Pl[(wv * 32 + mt * 16 + quad * 4 + r) * 72 + nt * 16 + lm] =
              f2bf(sf[mt][nt][r]);
#pragma unroll
    for (int kc = 0; kc < 2; kc++) {
      bf16x8 vf0 = *(bf16x8*)&Vtc[lm * 72 + kc * 32 + quad * 8];
      bf16x8 vf1 = *(bf16x8*)&Vtc[(16 + lm) * 72 + kc * 32 + quad * 8];
#pragma unroll
      for (int mt = 0; mt < 2; mt++) {
        bf16x8 pf = *(bf16x8*)&Pl[(wv * 32 + mt * 16 + lm) * 72 + kc * 32 + quad * 8];
        oacc[mt][0] = __builtin_amdgcn_mfma_f32_16x16x32_bf16(pf, vf0, oacc[mt][0], 0, 0, 0);
        oacc[mt][1] = __builtin_amdgcn_mfma_f32_16x16x32_bf16(pf, vf1, oacc[mt][1], 0, 0, 0);
      }
    }
  }
  float* ob = Opart + (size_t)(ks * 64 + bh) * 128 * 32;
#pragma unroll
  for (int mt = 0; mt < 2; mt++) {
#pragma unroll
    for (int r = 0; r < 4; r++) {
      int row = wv * 32 + mt * 16 + quad * 4 + r;
      ob[(size_t)row * 32 + lm] = oacc[mt][0][r];
      ob[(size_t)row * 32 + 16 + lm] = oacc[mt][1][r];
      if (lm == 0) {
        mpart[(size_t)(ks * 64 + bh) * 128 + row] = m_i[mt][r];
        lpart[(size_t)(ks * 64 + bh) * 128 + row] = l_i[mt][r];
      }
    }
  }
}

// ---------------------------------------------------------------------------
// Kernel: fusedB — attn1 combine + fc_o + K1/V1 projections. grid 32.
// ---------------------------------------------------------------------------
__global__ __launch_bounds__(256) void fusedB_kernel(
    const float* __restrict__ Opart, const float* __restrict__ mpart,
    const float* __restrict__ lpart, const short* __restrict__ qh,
    const short* __restrict__ Wo, const float* __restrict__ obias,
    const short* __restrict__ Wk, const float* __restrict__ kbias,
    const short* __restrict__ Wv, const float* __restrict__ vbias,
    short* __restrict__ khb, short* __restrict__ vhb) {
  __shared__ __align__(16) short Xl[64 * 136];
  __shared__ __align__(16) short Wl[128 * 136];
  int tid = threadIdx.x;
  int rb = blockIdx.x * 64;           // row in 2048 = b*128 + n
  int b = rb >> 7, n0 = rb & 127;
  {
    int rr = tid >> 2, hh = tid & 3;
    int n = n0 + rr;
    int bh = b * 4 + hh;
    float mv[8], lv[8], m = -1e30f;
#pragma unroll
    for (int s = 0; s < 8; s++) {
      mv[s] = mpart[(size_t)(s * 64 + bh) * 128 + n];
      lv[s] = lpart[(size_t)(s * 64 + bh) * 128 + n];
      m = fmaxf(m, mv[s]);
    }
    float l = 0.f;
    float oa[32];
#pragma unroll
    for (int d = 0; d < 32; d++) oa[d] = 0.f;
#pragma unroll
    for (int s = 0; s < 8; s++) {
      float w = __expf(mv[s] - m);
      l += lv[s] * w;
      const float* op = &Opart[((size_t)(s * 64 + bh) * 128 + n) * 32];
#pragma unroll
      for (int d4 = 0; d4 < 8; d4++) {
        float4 v = *(const float4*)&op[d4 * 4];
        oa[d4 * 4 + 0] += v.x * w; oa[d4 * 4 + 1] += v.y * w;
        oa[d4 * 4 + 2] += v.z * w; oa[d4 * 4 + 3] += v.w * w;
      }
    }
    float li = 1.f / l;
    const short* qp = &qh[((size_t)hh * 128 + n) * 32];
#pragma unroll
    for (int d = 0; d < 32; d++)
      Xl[rr * 136 + hh * 32 + d] = f2bf(bf2f(qp[d]) + oa[d] * li);
  }
  stage_w(Wl, Wo, tid);
  __syncthreads();   // B1: Xl(O) + Wl(Wo) ready
  int wv = tid >> 6, lane = tid & 63, lm = lane & 15, quad = lane >> 4;
  bf16x8 af[4];
  load_af(Xl, wv, lm, quad, af);
  floatx4 acc[8];
  gemm8(Wl, af, lm, quad, acc);
  // H = O + relu(acc + bias): in-place on Xl (wave-local rows)
#pragma unroll
  for (int nt = 0; nt < 8; nt++) {
    int col = nt * 16 + lm;
    float bn = obias[col];
#pragma unroll
    for (int r = 0; r < 4; r++) {
      int row = wv * 16 + quad * 4 + r;
      float ov = bf2f(Xl[row * 136 + col]);
      Xl[row * 136 + col] = f2bf(ov + fmaxf(acc[nt][r] + bn, 0.f));
    }
  }
  load_af(Xl, wv, lm, quad, af);   // af = H fragments; Xl now dead
  __syncthreads();   // B2: all waves done reading Wl(Wo)
  stage_w(Wl, Wk, tid);
  __syncthreads();   // B3
  gemm8(Wl, af, lm, quad, acc);
  store_sl(Xl, acc, kbias, wv, lm, quad);
  write_hs(Xl, khb, rb, 7, tid);
  __syncthreads();   // B4
  stage_w(Wl, Wv, tid);
  __syncthreads();   // B5
  gemm8(Wl, af, lm, quad, acc);
  store_sl(Xl, acc, vbias, wv, lm, quad);
  write_hs(Xl, vhb, rb, 7, tid);
}

// ---------------------------------------------------------------------------
// Kernel: MAB2 attention, register softmax. grid (64, 64). LDS ~42 KB.
// ---------------------------------------------------------------------------
__global__ __launch_bounds__(256) void attn2_kernel(
    const short* __restrict__ Qh, const short* __restrict__ Kh,
    const short* __restrict__ Vh, short* __restrict__ O) {
  __shared__ __align__(16) short Kl[128 * 40];
  __shared__ __align__(16) short Vt[32 * 136];
  __shared__ __align__(16) short Ql[64 * 40];
  __shared__ __align__(16) short Pl[64 * 136];
  int bh = blockIdx.x;
  int b = bh >> 2, h = bh & 3;
  int q0 = blockIdx.y * 64;
  int tid = threadIdx.x;
  int wv = tid >> 6, lane = tid & 63, lm = lane & 15, quad = lane >> 4;
  const short* kb = Kh + (size_t)bh * 128 * 32;
  const short* vb = Vh + (size_t)bh * 128 * 32;
  const short* qb = Qh + ((size_t)bh * OBS + q0) * 32;

  for (int i = tid * 8; i < 128 * 32; i += 2048) {
    int r = i >> 5, c = i & 31;
    *(int4*)&Kl[r * 40 + c] = *(const int4*)&kb[i];
  }
  for (int i = tid * 8; i < 64 * 32; i += 2048) {
    int r = i >> 5, c = i & 31;
    *(int4*)&Ql[r * 40 + c] = *(const int4*)&qb[i];
  }
  for (int i = tid * 8; i < 128 * 32; i += 2048) {
    int r = i >> 5, c = i & 31;
    int4 vv4 = *(const int4*)&vb[i];
    short* vv = (short*)&vv4;
#pragma unroll
    for (int j = 0; j < 8; j++) Vt[(c + j) * 136 + r] = vv[j];
  }
  __syncthreads();

  const float scale = 0.08838834764831845f;
  bf16x8 afrag = *(bf16x8*)&Ql[(wv * 16 + lm) * 40 + quad * 8];
  floatx4 sf[8];
#pragma unroll
  for (int nt = 0; nt < 8; nt++) {
    bf16x8 bfrag = *(bf16x8*)&Kl[(nt * 16 + lm) * 40 + quad * 8];
    floatx4 z = {0.f, 0.f, 0.f, 0.f};
    sf[nt] = __builtin_amdgcn_mfma_f32_16x16x32_bf16(afrag, bfrag, z, 0, 0, 0);
  }
#pragma unroll
  for (int nt = 0; nt < 8; nt++) sf[nt] *= scale;
  float linv[4];
#pragma unroll
  for (int r = 0; r < 4; r++) {
    float mx = sf[0][r];
#pragma unroll
    for (int nt = 1; nt < 8; nt++) mx = fmaxf(mx, sf[nt][r]);
    mx = fmaxf(mx, __shfl_xor(mx, 1));
    mx = fmaxf(mx, __shfl_xor(mx, 2));
    mx = fmaxf(mx, __shfl_xor(mx, 4));
    mx = fmaxf(mx, __shfl_xor(mx, 8));
    float sum = 0.f;
#pragma unroll
    for (int nt = 0; nt < 8; nt++) {
      float p = __expf(sf[nt][r] - mx);
      sf[nt][r] = p;
      sum += p;
    }
    sum += __shfl_xor(sum, 1);
    sum += __shfl_xor(sum, 2);
    sum += __shfl_xor(sum, 4);
    sum += __shfl_xor(sum, 8);
    linv[r] = 1.f / sum;
  }
#pragma unroll
  for (int nt = 0; nt < 8; nt++)
#pragma unroll
    for (int r = 0; r < 4; r++)
      Pl[(wv * 16 + quad * 4 + r) * 136 + nt * 16 + lm] = f2bf(sf[nt][r]);

  floatx4 oacc[2] = {{0.f, 0.f, 0.f, 0.f}, {0.f, 0.f, 0.f, 0.f}};
#pragma unroll
  for (int kc = 0; kc < 4; kc++) {
    bf16x8 pf = *(bf16x8*)&Pl[(wv * 16 + lm) * 136 + kc * 32 + quad * 8];
#pragma unroll
    for (int nt2 = 0; nt2 < 2; nt2++) {
      bf16x8 vf = *(bf16x8*)&Vt[(nt2 * 16 + lm) * 136 + kc * 32 + quad * 8];
      oacc[nt2] = __builtin_amdgcn_mfma_f32_16x16x32_bf16(pf, vf, oacc[nt2], 0, 0, 0);
    }
  }
  // stage O+Q residual in Pl rows (wave-local), then coalesced int4 store
  short* Ol = Pl;
#pragma unroll
  for (int nt2 = 0; nt2 < 2; nt2++) {
#pragma unroll
    for (int r = 0; r < 4; r++) {
      int qrow = wv * 16 + quad * 4 + r;
      float q = bf2f(Ql[qrow * 40 + nt2 * 16 + lm]);
      Ol[qrow * 136 + nt2 * 16 + lm] = f2bf(q + oacc[nt2][r] * linv[r]);
    }
  }
  int rr = tid >> 2, seg = tid & 3;      // wave-local Ol rows
  size_t o = ((size_t)b * OBS + q0 + rr) * 128 + h * 32 + seg * 8;
  *(int4*)&O[o] = *(int4*)&Ol[rr * 136 + seg * 8];
}

// ---------------------------------------------------------------------------
// Kernel: fusedC — fc_o + residual Z update + next layer's K0/V0/Q1.
// grid 1024 (64 rows). Wk==null => last layer (no projections).
// ---------------------------------------------------------------------------
__global__ __launch_bounds__(256) void fusedC_kernel(
    const short* __restrict__ Ob, const short* __restrict__ Wo,
    const float* __restrict__ obias, const float* __restrict__ mk,
    const float* __restrict__ Zin, float* __restrict__ Zout,
    const short* __restrict__ Wk, const float* __restrict__ kbias,
    short* __restrict__ Kb,
    const short* __restrict__ Wv, const float* __restrict__ vbias,
    short* __restrict__ Vb,
    const short* __restrict__ Wq, const float* __restrict__ qbias,
    short* __restrict__ Qb) {
  __shared__ __align__(16) short Xl[64 * 136];
  __shared__ __align__(16) short Wl[128 * 136];
  int tid = threadIdx.x;
  int rb = blockIdx.x * 64;
  int wv = tid >> 6, lane = tid & 63, lm = lane & 15, quad = lane >> 4;
  for (int i = tid * 8; i < 64 * 128; i += 2048) {
    int rr = i >> 7, c = i & 127;
    *(int4*)&Xl[rr * 136 + c] = *(const int4*)&Ob[(size_t)(rb + rr) * 136 - (size_t)(rb + rr) * 8 + c];
  }
  // NOTE: the expression above must be a plain row-major read of Ob:
  //   Ob[(rb+rr)*128 + c].  (136-8 == 128; kept explicit to avoid typo risk.)
  stage_w(Wl, Wo, tid);
  __syncthreads();   // B1
  bf16x8 af[4];
  load_af(Xl, wv, lm, quad, af);
  floatx4 acc[8];
  gemm8(Wl, af, lm, quad, acc);
  __syncthreads();   // B2: Wl free -> Fl
  float* Fl = (float*)Wl;   // 64 x 132 fp32
  // pass1 (wave-local Fl & Xl rows): Fl = Zin + (O + relu(acc+bias))*mk
#pragma unroll
  for (int nt = 0; nt < 8; nt++) {
    int col = nt * 16 + lm;
    float bn = obias[col];
#pragma unroll
    for (int r = 0; r < 4; r++) {
      int row = wv * 16 + quad * 4 + r;
      int gr = rb + row;
      float ov = bf2f(Xl[row * 136 + col]);
      float f = ov + fmaxf(acc[nt][r] + bn, 0.f);
      Fl[row * 132 + col] = Zin[(size_t)gr * 128 + col] + f * mk[gr];
    }
  }
  // pass2 (wave-local): Zout float4 + Xl <- new-Z bf16
  {
    int rr = tid >> 2, seg = tid & 3;
    int gr = rb + rr;
#pragma unroll
    for (int j = 0; j < 8; j++) {
      float4 f = *(float4*)&Fl[rr * 132 + seg * 32 + j * 4];
      *(float4*)&Zout[(size_t)gr * 128 + seg * 32 + j * 4] = f;
      if (Wk)
        *(short4*)&Xl[rr * 136 + seg * 32 + j * 4] =
            make_short4(f2bf(f.x), f2bf(f.y), f2bf(f.z), f2bf(f.w));
    }
  }
  if (Wk == nullptr) return;
  load_af(Xl, wv, lm, quad, af);   // af = new-Z fragments; Xl now dead
  __syncthreads();   // B3: Fl accesses done before stage_w overwrites
  stage_w(Wl, Wk, tid);
  __syncthreads();   // B4
  gemm8(Wl, af, lm, quad, acc);
  store_sl(Xl, acc, kbias, wv, lm, quad);
  write_hs(Xl, Kb, rb, 12, tid);
  __syncthreads();   // B5: all waves done reading Wl(Wk)
  stage_w(Wl, Wv, tid);
  __syncthreads();   // B6
  gemm8(Wl, af, lm, quad, acc);
  store_sl(Xl, acc, vbias, wv, lm, quad);
  write_hs(Xl, Vb, rb, 12, tid);
  __syncthreads();   // B7
  stage_w(Wl, Wq, tid);
  __syncthreads();   // B8
  gemm8(Wl, af, lm, quad, acc);
  store_sl(Xl, acc, qbias, wv, lm, quad);
  write_hs(Xl, Qb, rb, 12, tid);
}

// ---------------------------------------------------------------------------
extern "C" void kernel_launch(void* const* d_in, const int* in_sizes, int n_in,
                              void* d_out, int out_size, void* d_ws,
                              size_t ws_size, hipStream_t stream) {
  const float* cx    = (const float*)d_in[0];
  const float* value = (const float*)d_in[1];
  const float* mask  = (const float*)d_in[2];
  const float* iff_w = (const float*)d_in[4];
  const float* iff_b = (const float*)d_in[5];
  const float* indp  = (const float*)d_in[6];
  const float* q0w = (const float*)d_in[7];  const float* q0b = (const float*)d_in[8];
  const float* k0w = (const float*)d_in[9];  const float* k0b = (const float*)d_in[10];
  const float* v0w = (const float*)d_in[11]; const float* v0b = (const float*)d_in[12];
  const float* o0w = (const float*)d_in[13]; const float* o0b = (const float*)d_in[14];
  const float* q1w = (const float*)d_in[15]; const float* q1b = (const float*)d_in[16];
  const float* k1w = (const float*)d_in[17]; const float* k1b = (const float*)d_in[18];
  const float* v1w = (const float*)d_in[19]; const float* v1b = (const float*)d_in[20];
  const float* o1w = (const float*)d_in[21]; const float* o1b = (const float*)d_in[22];

  char* ws = (char*)d_ws;
  short* Wt    = (short*)ws;  ws += (size_t)24 * 16384 * 2;
  int*   order = (int*)ws;    ws += (size_t)NBATCH * OBS * 4;
  float* mk_g  = (float*)ws;  ws += (size_t)NBATCH * OBS * 4;
  float* Z     = (float*)ws;  ws += (size_t)NBATCH * OBS * DK * 4;
  short* Qb    = (short*)ws;  ws += (size_t)NBATCH * OBS * DK * 2;
  short* Kb    = (short*)ws;  ws += (size_t)NBATCH * OBS * DK * 2;
  short* Vb    = (short*)ws;  ws += (size_t)NBATCH * OBS * DK * 2;
  short* Ob    = (short*)ws;  ws += (size_t)NBATCH * OBS * DK * 2;
  short* qh_b  = (short*)ws;  ws += (size_t)3 * 128 * DK * 2;
  short* khb   = (short*)ws;  ws += (size_t)NBATCH * NH * 128 * DH * 2;
  short* vhb   = (short*)ws;  ws += (size_t)NBATCH * NH * 128 * DH * 2;
  float* Opart = (float*)ws;  ws += (size_t)8 * 64 * 128 * 32 * 4;
  float* mpart = (float*)ws;  ws += (size_t)8 * 64 * 128 * 4;
  float* lpart = (float*)ws;  ws += (size_t)8 * 64 * 128 * 4;

  float* outZ  = (float*)d_out;
  float* outMk = outZ + (size_t)NBATCH * OBS * DK;

  prep_build_kernel<<<40, 1024, 0, stream>>>(q0w, k0w, v0w, o0w, q1w, k1w,
                                             v1w, o1w, Wt, mask, order, mk_g,
                                             outMk);

  const short* W[3][8];
  for (int l = 0; l < 3; l++)
    for (int wi = 0; wi < 8; wi++) W[l][wi] = Wt + (size_t)(l * 8 + wi) * 16384;

  fusedA_kernel<<<1030, 256, 0, stream>>>(
      order, mk_g, cx, value, iff_w, iff_b, Z,
      W[0][1], k0b, Kb, W[0][2], v0b, Vb, W[0][4], q1b, Qb,
      indp, Wt, q0b, qh_b);

  for (int l = 0; l < 3; l++) {
    attn1_kernel<<<dim3(64, 8), 256, 0, stream>>>(
        qh_b + (size_t)l * 16384, Kb, Vb, mk_g, Opart, mpart, lpart);
    fusedB_kernel<<<32, 256, 0, stream>>>(
        Opart, mpart, lpart, qh_b + (size_t)l * 16384,
        W[l][3], o0b + (size_t)l * 128,
        W[l][5], k1b + (size_t)l * 128,
        W[l][6], v1b + (size_t)l * 128, khb, vhb);
    attn2_kernel<<<dim3(64, 64), 256, 0, stream>>>(Qb, khb, vhb, Ob);
    if (l < 2) {
      fusedC_kernel<<<1024, 256, 0, stream>>>(
          Ob, W[l][7], o1b + (size_t)l * 128, mk_g, Z, Z,
          W[l + 1][1], k0b + (size_t)(l + 1) * 128, Kb,
          W[l + 1][2], v0b + (size_t)(l + 1) * 128, Vb,
          W[l + 1][4], q1b + (size_t)(l + 1) * 128, Qb);
    } else {
      fusedC_kernel<<<1024, 256, 0, stream>>>(
          Ob, W[l][7], o1b + (size_t)l * 128, mk_g, Z, outZ,
          nullptr, nullptr, nullptr, nullptr, nullptr, nullptr,
          nullptr, nullptr, nullptr);
    }
  }
}